// Round 13
// baseline (210.473 us; speedup 1.0000x reference)
//
#include <hip/hip_runtime.h>

#define NN 50000
#define NE 800000
#define DIM 128
#define NC 32
#define CB 782            // dst buckets of 64 nodes: ceil(50000/64)
#define CCH 13            // scan chunk: 64*13 >= CB
#define EB 8192           // edges per scatter block
#define NBLK 98           // ceil(NE / EB)
#define BN_EPS 1e-5f
#define SELU_ALPHA 1.6732632423543772f
#define SELU_SCALE 1.0507009873554805f

typedef __attribute__((ext_vector_type(8))) short bf16x8;
typedef __attribute__((ext_vector_type(4))) float f32x4;

// acc[c] += sum_i hv[i] * wi[c]
#define FMA16(acc, hv, w0, w1, w2, w3)                                   \
    acc.x = fmaf(hv.x, w0.x, acc.x); acc.y = fmaf(hv.x, w0.y, acc.y);    \
    acc.z = fmaf(hv.x, w0.z, acc.z); acc.w = fmaf(hv.x, w0.w, acc.w);    \
    acc.x = fmaf(hv.y, w1.x, acc.x); acc.y = fmaf(hv.y, w1.y, acc.y);    \
    acc.z = fmaf(hv.y, w1.z, acc.z); acc.w = fmaf(hv.y, w1.w, acc.w);    \
    acc.x = fmaf(hv.z, w2.x, acc.x); acc.y = fmaf(hv.z, w2.y, acc.y);    \
    acc.z = fmaf(hv.z, w2.z, acc.z); acc.w = fmaf(hv.z, w2.w, acc.w);    \
    acc.x = fmaf(hv.w, w3.x, acc.x); acc.y = fmaf(hv.w, w3.y, acc.y);    \
    acc.z = fmaf(hv.w, w3.z, acc.z); acc.w = fmaf(hv.w, w3.w, acc.w);

#define BNSELU1(v)                                                        \
    v = v > 0.f ? SELU_SCALE * v : SELU_SCALE * SELU_ALPHA * (__expf(v) - 1.f);
#define BNSELU4(hv, sc, sh)                                               \
    hv.x = fmaf(hv.x, sc.x, sh.x); BNSELU1(hv.x)                          \
    hv.y = fmaf(hv.y, sc.y, sh.y); BNSELU1(hv.y)                          \
    hv.z = fmaf(hv.z, sc.z, sh.z); BNSELU1(hv.z)                          \
    hv.w = fmaf(hv.w, sc.w, sh.w); BNSELU1(hv.w)

// ---------- bf16 helpers (packed 2 per uint) ----------
__device__ __forceinline__ float bf_lo(unsigned u) { return __uint_as_float(u << 16); }
__device__ __forceinline__ float bf_hi(unsigned u) { return __uint_as_float(u & 0xffff0000u); }
__device__ __forceinline__ unsigned bf_round(float a) {
    unsigned ba = __float_as_uint(a);
    return (ba + 0x7fffu + ((ba >> 16) & 1u)) >> 16;   // round-nearest-even
}
__device__ __forceinline__ unsigned pack_bf16(float a, float b) {
    return bf_round(a) | (bf_round(b) << 16);
}

// inline edge-dtype flag: 1 if int64 (all odd words of first 64 are zero)
__device__ __forceinline__ int edge_flag(const int* raw) {
    int v = raw[2 * (threadIdx.x & 63) + 1];
    unsigned long long b = __ballot(v == 0);
    return b == 0xFFFFFFFFFFFFFFFFULL;
}

// ---------- merged prep: x->bf16, W1 transpose, zeroing, bucket histogram ----------
#define CVT_BLOCKS 6250   // NN*DIM/4 / 256
#define PREP_BLOCKS (CVT_BLOCKS + 65)
__global__ __launch_bounds__(256) void k_prep(
    const float4* __restrict__ in, uint2* __restrict__ out,
    const float* __restrict__ W1, ushort* __restrict__ w1t,
    float* __restrict__ z, int* __restrict__ done,
    const void* __restrict__ raw, int* __restrict__ cnt) {
    __shared__ int lh[CB];
    int bid = blockIdx.x, tid = threadIdx.x;
    if (bid < CVT_BLOCKS) {
        int i = bid * 256 + tid;
        float4 v = in[i];
        out[i] = make_uint2(pack_bf16(v.x, v.y), pack_bf16(v.z, v.w));
    } else if (bid < CVT_BLOCKS + 64) {
        int i = (bid - CVT_BLOCKS) * 256 + tid;
        int k = i >> 7, n = i & 127;
        w1t[n * 136 + k] = (ushort)bf_round(W1[i]);
    } else if (bid == CVT_BLOCKS + 64) {
        z[tid] = 0.f;  // ssum+ssq (2*DIM = 256)
        if (tid == 0) *done = 0;
    } else {
        int blk = bid - PREP_BLOCKS;
        for (int t = tid; t < CB; t += 256) lh[t] = 0;
        __syncthreads();
        int f = edge_flag((const int*)raw);
        const long long* r64 = (const long long*)raw;
        const int* r32 = (const int*)raw;
        int e0 = blk * EB;
        int n = min(EB, NE - e0);
        for (int i = tid; i < n; i += 256) {
            int d = f ? (int)r64[NE + e0 + i] : r32[NE + e0 + i];
            atomicAdd(&lh[d >> 6], 1);
        }
        __syncthreads();
        for (int t = tid; t < CB; t += 256) cnt[t * NBLK + blk] = lh[t];
    }
}

// ---------- fused scan: per-bucket row scan + (last block) bucket-total scan ----------
// cnt (orig) -> cnts (exclusive over blocks); tot[b]; last block: cbase, rowptr[NN].
__global__ void k_scan2(const int* __restrict__ cnt, int* __restrict__ cnts,
                        int* __restrict__ tot, int* __restrict__ cbase,
                        int* __restrict__ rowptr, int* __restrict__ done) {
    int b = blockIdx.x;
    const int* row = cnt + b * NBLK;
    int* rows = cnts + b * NBLK;
    int l = threadIdx.x;  // 64
    int p0 = 2 * l, p1 = 2 * l + 1;
    int a0 = (p0 < NBLK) ? row[p0] : 0;
    int a1 = (p1 < NBLK) ? row[p1] : 0;
    int s = a0 + a1, inc = s;
    #pragma unroll
    for (int off = 1; off < 64; off <<= 1) {
        int u = __shfl_up(inc, off, 64);
        if (l >= off) inc += u;
    }
    int ex = inc - s;
    if (p0 < NBLK) rows[p0] = ex;
    if (p1 < NBLK) rows[p1] = ex + a0;
    if (l == 63) tot[b] = inc;

    // last-arriving block performs the bucket-total scan (deterministic result)
    __threadfence();
    int lastv = 0;
    if (l == 0) lastv = (atomicAdd(done, 1) == CB - 1) ? 1 : 0;
    lastv = __shfl(lastv, 0, 64);
    if (!lastv) return;
    __threadfence();  // acquire: all tot[] writes now visible

    int base = l * CCH;
    int loc[CCH];
    int s2 = 0;
    #pragma unroll
    for (int i = 0; i < CCH; ++i) {
        int idx = base + i;
        int v = (idx < CB) ? tot[idx] : 0;
        loc[i] = s2; s2 += v;
    }
    int inc2 = s2;
    #pragma unroll
    for (int off = 1; off < 64; off <<= 1) {
        int u = __shfl_up(inc2, off, 64);
        if (l >= off) inc2 += u;
    }
    int ex2 = inc2 - s2;
    #pragma unroll
    for (int i = 0; i < CCH; ++i) {
        int idx = base + i;
        if (idx < CB) cbase[idx] = ex2 + loc[i];
    }
    if (l == 63) { cbase[CB] = inc2; rowptr[NN] = NE; }
}

// ---------- scatter: single edge pass; counts come from cnt/cnts ----------
__global__ __launch_bounds__(256) void k_cscatter2(const void* __restrict__ raw,
                                                   const int* __restrict__ cnt,
                                                   const int* __restrict__ cnts,
                                                   const int* __restrict__ cbase,
                                                   unsigned* __restrict__ pairs) {
    __shared__ int lbase[CB], lcur[CB], gbase[CB];
    __shared__ unsigned lp[EB];
    __shared__ int lh[CB];
    int blk = blockIdx.x, tid = threadIdx.x;
    for (int t = tid; t < CB; t += 256) {
        lh[t] = cnt[t * NBLK + blk];
        gbase[t] = cbase[t] + cnts[t * NBLK + blk];
    }
    __syncthreads();
    if (tid < 64) {  // wave 0: scan lh -> lbase
        int base = tid * CCH;
        int loc[CCH];
        int s = 0;
        #pragma unroll
        for (int i = 0; i < CCH; ++i) {
            int idx = base + i;
            int v = (idx < CB) ? lh[idx] : 0;
            loc[i] = s; s += v;
        }
        int inc = s;
        #pragma unroll
        for (int off = 1; off < 64; off <<= 1) {
            int u = __shfl_up(inc, off, 64);
            if (tid >= off) inc += u;
        }
        int ex = inc - s;
        #pragma unroll
        for (int i = 0; i < CCH; ++i) {
            int idx = base + i;
            if (idx < CB) lbase[idx] = ex + loc[i];
        }
    }
    __syncthreads();
    for (int t = tid; t < CB; t += 256) lcur[t] = lbase[t];
    __syncthreads();
    int f = edge_flag((const int*)raw);
    const long long* r64 = (const long long*)raw;
    const int* r32 = (const int*)raw;
    int e0 = blk * EB;
    int n = min(EB, NE - e0);
    for (int i = tid; i < n; i += 256) {
        int d = f ? (int)r64[NE + e0 + i] : r32[NE + e0 + i];
        int sv = f ? (int)r64[e0 + i] : r32[e0 + i];
        int b = d >> 6;
        int p = atomicAdd(&lcur[b], 1);
        lp[p] = (unsigned)sv | ((unsigned)(d & 63) << 16) | ((unsigned)b << 22);
    }
    __syncthreads();
    for (int i = tid; i < n; i += 256) {
        unsigned pr = lp[i];
        int b = pr >> 22;
        pairs[gbase[b] + (i - lbase[b])] = pr;
    }
}

__global__ __launch_bounds__(256) void k_bucket(const unsigned* __restrict__ pairs,
                                                const int* __restrict__ cbase,
                                                int* __restrict__ rowptr,
                                                ushort* __restrict__ eidx) {
    __shared__ int cnt[64], cur[64];
    int b = blockIdx.x;
    int tid = threadIdx.x;
    if (tid < 64) cnt[tid] = 0;
    __syncthreads();
    int lo = cbase[b], hi = cbase[b + 1];
    for (int i = lo + tid; i < hi; i += 256)
        atomicAdd(&cnt[(pairs[i] >> 16) & 63], 1);
    __syncthreads();
    if (tid < 64) {
        int v = cnt[tid];
        int inc = v;
        #pragma unroll
        for (int off = 1; off < 64; off <<= 1) {
            int u = __shfl_up(inc, off, 64);
            if (tid >= off) inc += u;
        }
        int ex = inc - v;
        cur[tid] = ex;
        int node = b * 64 + tid;
        if (node < NN) rowptr[node] = lo + ex;
    }
    __syncthreads();
    for (int i = lo + tid; i < hi; i += 256) {
        unsigned pr = pairs[i];
        int p = atomicAdd(&cur[(pr >> 16) & 63], 1);
        eidx[lo + p] = (ushort)(pr & 0xFFFFu);
    }
}

// ---------- bf16 aggregation: out[i] = in[i] + sum_{j in neigh(i)} in[j] ----------
__global__ __launch_bounds__(256) void k_gather_bf(const unsigned* __restrict__ in,
                                                   unsigned* __restrict__ out,
                                                   const int* __restrict__ rowptr,
                                                   const ushort* __restrict__ eidx) {
    int node = blockIdx.x * 4 + (threadIdx.x >> 6);
    if (node >= NN) return;
    int lane = threadIdx.x & 63;
    unsigned su = in[(size_t)node * 64 + lane];  // self-loop
    float2 acc = {bf_lo(su), bf_hi(su)};
    int b = rowptr[node], e = rowptr[node + 1];
    int j = b;
    for (; j + 7 < e; j += 8) {
        int s0 = eidx[j],     s1 = eidx[j + 1], s2 = eidx[j + 2], s3 = eidx[j + 3];
        int s4 = eidx[j + 4], s5 = eidx[j + 5], s6 = eidx[j + 6], s7 = eidx[j + 7];
        unsigned u0 = in[(size_t)s0 * 64 + lane];
        unsigned u1 = in[(size_t)s1 * 64 + lane];
        unsigned u2 = in[(size_t)s2 * 64 + lane];
        unsigned u3 = in[(size_t)s3 * 64 + lane];
        unsigned u4 = in[(size_t)s4 * 64 + lane];
        unsigned u5 = in[(size_t)s5 * 64 + lane];
        unsigned u6 = in[(size_t)s6 * 64 + lane];
        unsigned u7 = in[(size_t)s7 * 64 + lane];
        acc.x += bf_lo(u0) + bf_lo(u1) + bf_lo(u2) + bf_lo(u3)
               + bf_lo(u4) + bf_lo(u5) + bf_lo(u6) + bf_lo(u7);
        acc.y += bf_hi(u0) + bf_hi(u1) + bf_hi(u2) + bf_hi(u3)
               + bf_hi(u4) + bf_hi(u5) + bf_hi(u6) + bf_hi(u7);
    }
    for (; j + 3 < e; j += 4) {
        int s0 = eidx[j], s1 = eidx[j + 1], s2 = eidx[j + 2], s3 = eidx[j + 3];
        unsigned u0 = in[(size_t)s0 * 64 + lane];
        unsigned u1 = in[(size_t)s1 * 64 + lane];
        unsigned u2 = in[(size_t)s2 * 64 + lane];
        unsigned u3 = in[(size_t)s3 * 64 + lane];
        acc.x += bf_lo(u0) + bf_lo(u1) + bf_lo(u2) + bf_lo(u3);
        acc.y += bf_hi(u0) + bf_hi(u1) + bf_hi(u2) + bf_hi(u3);
    }
    for (; j < e; ++j) {
        unsigned u0 = in[(size_t)eidx[j] * 64 + lane];
        acc.x += bf_lo(u0);
        acc.y += bf_hi(u0);
    }
    out[(size_t)node * 64 + lane] = pack_bf16(acc.x, acc.y);
}

// ---------- GEMM1 via MFMA: h1 = hBb @ W1 + b1, fused BN sum/sumsq ----------
__global__ __launch_bounds__(256) void k_gemm1(
    const unsigned* __restrict__ hBb, const ushort* __restrict__ w1t,
    const float* __restrict__ b1, float* __restrict__ h1,
    float* __restrict__ ssum, float* __restrict__ ssq) {
    __shared__ __align__(16) ushort wT[DIM * 136];
    __shared__ float redS[4 * DIM];
    __shared__ float redQ[4 * DIM];
    int tid = threadIdx.x;
    for (int i = tid; i < DIM * 136 / 8; i += 256)
        ((uint4*)wT)[i] = ((const uint4*)w1t)[i];
    for (int i = tid; i < 4 * DIM; i += 256) { redS[i] = 0.f; redQ[i] = 0.f; }
    __syncthreads();

    int wid = tid >> 6, lane = tid & 63;
    int cl = lane & 15, kg = lane >> 4;
    int tile = blockIdx.x * 4 + wid;
    if (tile < NN / 16) {
        int rbase = tile * 16;
        const uint4* arow = (const uint4*)(hBb + (size_t)(rbase + cl) * 64);
        f32x4 acc[8];
        #pragma unroll
        for (int ct = 0; ct < 8; ++ct) acc[ct] = (f32x4){0.f, 0.f, 0.f, 0.f};
        #pragma unroll
        for (int kk = 0; kk < 4; ++kk) {
            union { uint4 u; bf16x8 f; } a;
            a.u = arow[kk * 4 + kg];
            #pragma unroll
            for (int ct = 0; ct < 8; ++ct) {
                union { uint4 u; bf16x8 f; } bb;
                bb.u = *(const uint4*)&wT[(ct * 16 + cl) * 136 + kk * 32 + kg * 8];
                acc[ct] = __builtin_amdgcn_mfma_f32_16x16x32_bf16(a.f, bb.f, acc[ct], 0, 0, 0);
            }
        }
        #pragma unroll
        for (int ct = 0; ct < 8; ++ct) {
            int col = ct * 16 + cl;
            float bias = b1[col];
            float s = 0.f, q = 0.f;
            #pragma unroll
            for (int i = 0; i < 4; ++i) {
                float v = acc[ct][i] + bias;
                h1[(size_t)(rbase + kg * 4 + i) * DIM + col] = v;
                s += v; q += v * v;
            }
            s += __shfl_xor(s, 16); s += __shfl_xor(s, 32);
            q += __shfl_xor(q, 16); q += __shfl_xor(q, 32);
            if (kg == 0) { redS[wid * DIM + col] = s; redQ[wid * DIM + col] = q; }
        }
    }
    __syncthreads();
    if (tid < DIM) {
        float S = redS[tid] + redS[DIM + tid] + redS[2 * DIM + tid] + redS[3 * DIM + tid];
        float Q = redQ[tid] + redQ[DIM + tid] + redQ[2 * DIM + tid] + redQ[3 * DIM + tid];
        atomicAdd(&ssum[tid], S);
        atomicAdd(&ssq[tid], Q);
    }
}

// ---------- GEMM2 with inline BN-stats finalize + fused BN+SELU on input ----------
__global__ __launch_bounds__(256) void k_gemm2(const float* __restrict__ h,
                                               const float* __restrict__ W2,
                                               const float* __restrict__ ssum,
                                               const float* __restrict__ ssq,
                                               const float* __restrict__ gamma,
                                               const float* __restrict__ beta,
                                               unsigned* __restrict__ tb) {
    __shared__ float w[DIM * NC];
    __shared__ float scl[DIM], shl[DIM];
    for (int i = threadIdx.x * 4; i < DIM * NC; i += 1024)
        *(float4*)&w[i] = *(const float4*)&W2[i];
    if (threadIdx.x < DIM) {
        int c = threadIdx.x;
        float mu = ssum[c] / (float)NN;
        float var = ssq[c] / (float)NN - mu * mu;
        float rs = rsqrtf(var + BN_EPS);
        float sc = rs * gamma[c];
        scl[c] = sc;
        shl[c] = beta[c] - mu * sc;
    }
    __syncthreads();

    int c0 = (threadIdx.x & 7) * 4;
    int rg = threadIdx.x >> 3;  // 0..31
    int r0 = blockIdx.x * 128 + rg * 4;
    if (r0 >= NN) return;
    const float* h0 = h + (size_t)r0 * DIM;
    float4 a0 = {0, 0, 0, 0}, a1 = {0, 0, 0, 0}, a2 = {0, 0, 0, 0}, a3 = {0, 0, 0, 0};
    #pragma unroll 4
    for (int k4 = 0; k4 < DIM / 4; ++k4) {
        float4 sc = *(const float4*)&scl[k4 * 4];
        float4 sh = *(const float4*)&shl[k4 * 4];
        float4 hv0 = *(const float4*)&h0[k4 * 4];
        float4 hv1 = *(const float4*)&h0[DIM + k4 * 4];
        float4 hv2 = *(const float4*)&h0[2 * DIM + k4 * 4];
        float4 hv3 = *(const float4*)&h0[3 * DIM + k4 * 4];
        BNSELU4(hv0, sc, sh)
        BNSELU4(hv1, sc, sh)
        BNSELU4(hv2, sc, sh)
        BNSELU4(hv3, sc, sh)
        float4 w0 = *(const float4*)&w[(k4 * 4 + 0) * NC + c0];
        float4 w1 = *(const float4*)&w[(k4 * 4 + 1) * NC + c0];
        float4 w2 = *(const float4*)&w[(k4 * 4 + 2) * NC + c0];
        float4 w3 = *(const float4*)&w[(k4 * 4 + 3) * NC + c0];
        FMA16(a0, hv0, w0, w1, w2, w3)
        FMA16(a1, hv1, w0, w1, w2, w3)
        FMA16(a2, hv2, w0, w1, w2, w3)
        FMA16(a3, hv3, w0, w1, w2, w3)
    }
    ((uint2*)tb)[((size_t)r0 * 16 + c0 / 2) / 2]       = make_uint2(pack_bf16(a0.x, a0.y), pack_bf16(a0.z, a0.w));
    ((uint2*)tb)[((size_t)(r0 + 1) * 16 + c0 / 2) / 2] = make_uint2(pack_bf16(a1.x, a1.y), pack_bf16(a1.z, a1.w));
    ((uint2*)tb)[((size_t)(r0 + 2) * 16 + c0 / 2) / 2] = make_uint2(pack_bf16(a2.x, a2.y), pack_bf16(a2.z, a2.w));
    ((uint2*)tb)[((size_t)(r0 + 3) * 16 + c0 / 2) / 2] = make_uint2(pack_bf16(a3.x, a3.y), pack_bf16(a3.z, a3.w));
}

// ---------- fused gather(bf16, 32-wide) + bias + softmax ----------
__global__ __launch_bounds__(256) void k_gsoftmax(const unsigned* __restrict__ tb,
                                                  const float* __restrict__ b2,
                                                  const int* __restrict__ rowptr,
                                                  const ushort* __restrict__ eidx,
                                                  float* __restrict__ out) {
    int node = blockIdx.x * 4 + (threadIdx.x >> 6);
    if (node >= NN) return;
    int lane = threadIdx.x & 63;
    int c2 = lane & 15;       // class pair index
    int g = lane >> 4;        // 0..3: edge-list quarter
    float2 acc = {0.f, 0.f};
    if (g == 0) {             // self-loop once
        unsigned u = tb[(size_t)node * 16 + c2];
        acc.x = bf_lo(u); acc.y = bf_hi(u);
    }
    int b = rowptr[node], e = rowptr[node + 1];
    int j = b + g;
    for (; j + 4 < e; j += 8) {
        int s0 = eidx[j];
        int s1 = eidx[j + 4];
        unsigned u0 = tb[(size_t)s0 * 16 + c2];
        unsigned u1 = tb[(size_t)s1 * 16 + c2];
        acc.x += bf_lo(u0) + bf_lo(u1);
        acc.y += bf_hi(u0) + bf_hi(u1);
    }
    if (j < e) {
        unsigned u = tb[(size_t)eidx[j] * 16 + c2];
        acc.x += bf_lo(u);
        acc.y += bf_hi(u);
    }
    acc.x += __shfl_xor(acc.x, 16); acc.x += __shfl_xor(acc.x, 32);
    acc.y += __shfl_xor(acc.y, 16); acc.y += __shfl_xor(acc.y, 32);
    acc.x += b2[2 * c2];
    acc.y += b2[2 * c2 + 1];
    float m = fmaxf(acc.x, acc.y);
    #pragma unroll
    for (int off = 8; off; off >>= 1) m = fmaxf(m, __shfl_xor(m, off, 16));
    float2 ex = {__expf(acc.x - m), __expf(acc.y - m)};
    float s = ex.x + ex.y;
    #pragma unroll
    for (int off = 8; off; off >>= 1) s += __shfl_xor(s, off, 16);
    float inv = 1.f / s;
    if (g == 0)
        *(float2*)&out[(size_t)node * NC + 2 * c2] = make_float2(ex.x * inv, ex.y * inv);
}

extern "C" void kernel_launch(void* const* d_in, const int* in_sizes, int n_in,
                              void* d_out, int out_size, void* d_ws, size_t ws_size,
                              hipStream_t stream) {
    const float* x     = (const float*)d_in[0];
    const void*  eraw  = d_in[1];
    const float* W1    = (const float*)d_in[2];
    const float* b1    = (const float*)d_in[3];
    const float* gamma = (const float*)d_in[4];
    const float* beta  = (const float*)d_in[5];
    const float* W2    = (const float*)d_in[6];
    const float* b2    = (const float*)d_in[7];
    float* out = (float*)d_out;

    // workspace layout (16B-aligned; all block sizes multiples of 4 ints)
    float*    regA = (float*)d_ws;                    // 25.6 MB
    unsigned* xb   = (unsigned*)regA;                 // NN*64 uints (bf16 x)
    unsigned* hAb  = xb + (size_t)NN * 64;            // NN*64 uints (bf16 agg1)
    float*    h1   = regA;                            // gemm1 out, overlays xb/hAb
    float*    regB = regA + (size_t)NN * DIM;         // 25.6 MB
    unsigned* pairs= (unsigned*)regB;                 // NE uints (CSR phase only)
    unsigned* hBb  = (unsigned*)regB;                 // NN*64 uints (bf16 agg2)
    unsigned* tb   = (unsigned*)(regB + (size_t)NN * 64);  // NN*16 uints (bf16 t)
    ushort* eidx = (ushort*)(regB + (size_t)NN * DIM); // NE ushorts (= 400000 ints)
    int* rowptr = (int*)(eidx + NE);                  // NN+4
    int* cnt    = rowptr + NN + 4;                    // CB*NBLK = 76636
    int* cnts   = cnt + CB * NBLK;                    // CB*NBLK
    int* tot    = cnts + CB * NBLK;                   // 784
    int* cbase  = tot + 784;                          // 784 (uses CB+1)
    int* done   = cbase + 784;                        // 4
    float* ssum  = (float*)(done + 4);                // DIM
    float* ssq   = ssum + DIM;                        // DIM
    ushort* w1t  = (ushort*)(ssq + DIM);              // 128*136 bf16

    // merged prep (cvt + w1t + zero + bucket-histogram) — fills the machine
    k_prep<<<PREP_BLOCKS + NBLK, 256, 0, stream>>>(
        (const float4*)x, (uint2*)xb, W1, w1t, ssum, done, eraw, cnt);
    // fused per-bucket scan + last-block bucket-total scan
    k_scan2<<<CB, 64, 0, stream>>>(cnt, cnts, tot, cbase, rowptr, done);
    k_cscatter2<<<NBLK, 256, 0, stream>>>(eraw, cnt, cnts, cbase, pairs);
    k_bucket<<<CB, 256, 0, stream>>>(pairs, cbase, rowptr, eidx);

    const int gather_blocks = (NN + 3) / 4;
    // agg1: hAb = xb + gather(xb)        (bf16)
    k_gather_bf<<<gather_blocks, 256, 0, stream>>>(xb, hAb, rowptr, eidx);
    // agg2: hBb = hAb + gather(hAb)      (bf16, feeds MFMA)
    k_gather_bf<<<gather_blocks, 256, 0, stream>>>(hAb, hBb, rowptr, eidx);
    // gemm1 (MFMA) + BN stats: h1 = hBb @ W1 + b1
    k_gemm1<<<(NN / 16 + 3) / 4, 256, 0, stream>>>(hBb, w1t, b1, h1, ssum, ssq);
    // layer 2 reordered: tb = bf16(selu(bn(h1)) @ W2), out = softmax(gather(tb) + b2)
    k_gemm2<<<(NN + 127) / 128, 256, 0, stream>>>(h1, W2, ssum, ssq, gamma, beta, tb);
    k_gsoftmax<<<gather_blocks, 256, 0, stream>>>(tb, b2, rowptr, eidx, out);
}

// Round 14
// 201.959 us; speedup vs baseline: 1.0422x; 1.0422x over previous
//
#include <hip/hip_runtime.h>

#define NN 50000
#define NE 800000
#define DIM 128
#define NC 32
#define CB 782            // dst buckets of 64 nodes: ceil(50000/64)
#define CCH 13            // scan chunk: 64*13 >= CB
#define EB 8192           // edges per scatter block
#define NBLK 98           // ceil(NE / EB)
#define BN_EPS 1e-5f
#define SELU_ALPHA 1.6732632423543772f
#define SELU_SCALE 1.0507009873554805f

typedef __attribute__((ext_vector_type(8))) short bf16x8;
typedef __attribute__((ext_vector_type(4))) float f32x4;

// acc[c] += sum_i hv[i] * wi[c]
#define FMA16(acc, hv, w0, w1, w2, w3)                                   \
    acc.x = fmaf(hv.x, w0.x, acc.x); acc.y = fmaf(hv.x, w0.y, acc.y);    \
    acc.z = fmaf(hv.x, w0.z, acc.z); acc.w = fmaf(hv.x, w0.w, acc.w);    \
    acc.x = fmaf(hv.y, w1.x, acc.x); acc.y = fmaf(hv.y, w1.y, acc.y);    \
    acc.z = fmaf(hv.y, w1.z, acc.z); acc.w = fmaf(hv.y, w1.w, acc.w);    \
    acc.x = fmaf(hv.z, w2.x, acc.x); acc.y = fmaf(hv.z, w2.y, acc.y);    \
    acc.z = fmaf(hv.z, w2.z, acc.z); acc.w = fmaf(hv.z, w2.w, acc.w);    \
    acc.x = fmaf(hv.w, w3.x, acc.x); acc.y = fmaf(hv.w, w3.y, acc.y);    \
    acc.z = fmaf(hv.w, w3.z, acc.z); acc.w = fmaf(hv.w, w3.w, acc.w);

#define BNSELU1(v)                                                        \
    v = v > 0.f ? SELU_SCALE * v : SELU_SCALE * SELU_ALPHA * (__expf(v) - 1.f);
#define BNSELU4(hv, sc, sh)                                               \
    hv.x = fmaf(hv.x, sc.x, sh.x); BNSELU1(hv.x)                          \
    hv.y = fmaf(hv.y, sc.y, sh.y); BNSELU1(hv.y)                          \
    hv.z = fmaf(hv.z, sc.z, sh.z); BNSELU1(hv.z)                          \
    hv.w = fmaf(hv.w, sc.w, sh.w); BNSELU1(hv.w)

// ---------- bf16 helpers (packed 2 per uint) ----------
__device__ __forceinline__ float bf_lo(unsigned u) { return __uint_as_float(u << 16); }
__device__ __forceinline__ float bf_hi(unsigned u) { return __uint_as_float(u & 0xffff0000u); }
__device__ __forceinline__ unsigned bf_round(float a) {
    unsigned ba = __float_as_uint(a);
    return (ba + 0x7fffu + ((ba >> 16) & 1u)) >> 16;   // round-nearest-even
}
__device__ __forceinline__ unsigned pack_bf16(float a, float b) {
    return bf_round(a) | (bf_round(b) << 16);
}

// inline edge-dtype flag: 1 if int64 (all odd words of first 64 are zero)
__device__ __forceinline__ int edge_flag(const int* raw) {
    int v = raw[2 * (threadIdx.x & 63) + 1];
    unsigned long long b = __ballot(v == 0);
    return b == 0xFFFFFFFFFFFFFFFFULL;
}

// ---------- merged prep: x->bf16, W1 transpose, ssum zero, bucket histogram ----------
#define CVT_BLOCKS 6250   // NN*DIM/4 / 256
#define PREP_BLOCKS (CVT_BLOCKS + 65)
__global__ __launch_bounds__(256) void k_prep(
    const float4* __restrict__ in, uint2* __restrict__ out,
    const float* __restrict__ W1, ushort* __restrict__ w1t,
    float* __restrict__ z, const void* __restrict__ raw, int* __restrict__ cnt) {
    __shared__ int lh[CB];
    int bid = blockIdx.x, tid = threadIdx.x;
    if (bid < CVT_BLOCKS) {
        int i = bid * 256 + tid;
        float4 v = in[i];
        out[i] = make_uint2(pack_bf16(v.x, v.y), pack_bf16(v.z, v.w));
    } else if (bid < CVT_BLOCKS + 64) {
        int i = (bid - CVT_BLOCKS) * 256 + tid;
        int k = i >> 7, n = i & 127;
        w1t[n * 136 + k] = (ushort)bf_round(W1[i]);
    } else if (bid == CVT_BLOCKS + 64) {
        z[tid] = 0.f;  // ssum+ssq (2*DIM = 256)
    } else {
        int blk = bid - PREP_BLOCKS;
        for (int t = tid; t < CB; t += 256) lh[t] = 0;
        __syncthreads();
        int f = edge_flag((const int*)raw);
        const long long* r64 = (const long long*)raw;
        const int* r32 = (const int*)raw;
        int e0 = blk * EB;
        int n = min(EB, NE - e0);
        for (int i = tid; i < n; i += 256) {
            int d = f ? (int)r64[NE + e0 + i] : r32[NE + e0 + i];
            atomicAdd(&lh[d >> 6], 1);
        }
        __syncthreads();
        for (int t = tid; t < CB; t += 256) cnt[t * NBLK + blk] = lh[t];
    }
}

__global__ void k_colscan(int* __restrict__ cnt, int* __restrict__ tot) {
    int b = blockIdx.x;
    int* row = cnt + b * NBLK;
    int l = threadIdx.x;  // 64
    int p0 = 2 * l, p1 = 2 * l + 1;
    int a0 = (p0 < NBLK) ? row[p0] : 0;
    int a1 = (p1 < NBLK) ? row[p1] : 0;
    int s = a0 + a1, inc = s;
    #pragma unroll
    for (int off = 1; off < 64; off <<= 1) {
        int u = __shfl_up(inc, off, 64);
        if (l >= off) inc += u;
    }
    int ex = inc - s;
    if (p0 < NBLK) row[p0] = ex;
    if (p1 < NBLK) row[p1] = ex + a0;
    if (l == 63) tot[b] = inc;
}

__global__ void k_cscan(const int* __restrict__ tot, int* __restrict__ cbase,
                        int* __restrict__ rowptr) {
    int lane = threadIdx.x;  // 64
    int base = lane * CCH;
    int loc[CCH];
    int s = 0;
    #pragma unroll
    for (int i = 0; i < CCH; ++i) {
        int idx = base + i;
        int v = (idx < CB) ? tot[idx] : 0;
        loc[i] = s; s += v;
    }
    int inc = s;
    #pragma unroll
    for (int off = 1; off < 64; off <<= 1) {
        int u = __shfl_up(inc, off, 64);
        if (lane >= off) inc += u;
    }
    int ex = inc - s;
    #pragma unroll
    for (int i = 0; i < CCH; ++i) {
        int idx = base + i;
        if (idx < CB) cbase[idx] = ex + loc[i];
    }
    if (lane == 63) { cbase[CB] = inc; rowptr[NN] = NE; }
}

__global__ __launch_bounds__(256) void k_cscatter2(const void* __restrict__ raw,
                                                   const int* __restrict__ cnt,
                                                   const int* __restrict__ cbase,
                                                   unsigned* __restrict__ pairs) {
    __shared__ int lh[CB], lbase[CB], lcur[CB], gbase[CB];
    __shared__ unsigned lp[EB];
    int blk = blockIdx.x, tid = threadIdx.x;
    for (int t = tid; t < CB; t += 256) {
        lh[t] = 0;
        gbase[t] = cbase[t] + cnt[t * NBLK + blk];
    }
    __syncthreads();
    int f = edge_flag((const int*)raw);
    const long long* r64 = (const long long*)raw;
    const int* r32 = (const int*)raw;
    int e0 = blk * EB;
    int n = min(EB, NE - e0);
    for (int i = tid; i < n; i += 256) {
        int d = f ? (int)r64[NE + e0 + i] : r32[NE + e0 + i];
        atomicAdd(&lh[d >> 6], 1);
    }
    __syncthreads();
    if (tid < 64) {  // wave 0: scan lh -> lbase
        int base = tid * CCH;
        int loc[CCH];
        int s = 0;
        #pragma unroll
        for (int i = 0; i < CCH; ++i) {
            int idx = base + i;
            int v = (idx < CB) ? lh[idx] : 0;
            loc[i] = s; s += v;
        }
        int inc = s;
        #pragma unroll
        for (int off = 1; off < 64; off <<= 1) {
            int u = __shfl_up(inc, off, 64);
            if (tid >= off) inc += u;
        }
        int ex = inc - s;
        #pragma unroll
        for (int i = 0; i < CCH; ++i) {
            int idx = base + i;
            if (idx < CB) lbase[idx] = ex + loc[i];
        }
    }
    __syncthreads();
    for (int t = tid; t < CB; t += 256) lcur[t] = lbase[t];
    __syncthreads();
    for (int i = tid; i < n; i += 256) {
        int d = f ? (int)r64[NE + e0 + i] : r32[NE + e0 + i];
        int sv = f ? (int)r64[e0 + i] : r32[e0 + i];
        int b = d >> 6;
        int p = atomicAdd(&lcur[b], 1);
        lp[p] = (unsigned)sv | ((unsigned)(d & 63) << 16) | ((unsigned)b << 22);
    }
    __syncthreads();
    for (int i = tid; i < n; i += 256) {
        unsigned pr = lp[i];
        int b = pr >> 22;
        pairs[gbase[b] + (i - lbase[b])] = pr;
    }
}

__global__ __launch_bounds__(256) void k_bucket(const unsigned* __restrict__ pairs,
                                                const int* __restrict__ cbase,
                                                int* __restrict__ rowptr,
                                                ushort* __restrict__ eidx) {
    __shared__ int cnt[64], cur[64];
    int b = blockIdx.x;
    int tid = threadIdx.x;
    if (tid < 64) cnt[tid] = 0;
    __syncthreads();
    int lo = cbase[b], hi = cbase[b + 1];
    for (int i = lo + tid; i < hi; i += 256)
        atomicAdd(&cnt[(pairs[i] >> 16) & 63], 1);
    __syncthreads();
    if (tid < 64) {
        int v = cnt[tid];
        int inc = v;
        #pragma unroll
        for (int off = 1; off < 64; off <<= 1) {
            int u = __shfl_up(inc, off, 64);
            if (tid >= off) inc += u;
        }
        int ex = inc - v;
        cur[tid] = ex;
        int node = b * 64 + tid;
        if (node < NN) rowptr[node] = lo + ex;
    }
    __syncthreads();
    for (int i = lo + tid; i < hi; i += 256) {
        unsigned pr = pairs[i];
        int p = atomicAdd(&cur[(pr >> 16) & 63], 1);
        eidx[lo + p] = (ushort)(pr & 0xFFFFu);
    }
}

// ---------- bf16 aggregation: out[i] = in[i] + sum_{j in neigh(i)} in[j] ----------
// one wave per node; lane owns 2 cols via one packed uint. fp32 accumulate.
__global__ __launch_bounds__(256) void k_gather_bf(const unsigned* __restrict__ in,
                                                   unsigned* __restrict__ out,
                                                   const int* __restrict__ rowptr,
                                                   const ushort* __restrict__ eidx) {
    int node = blockIdx.x * 4 + (threadIdx.x >> 6);
    if (node >= NN) return;
    int lane = threadIdx.x & 63;
    unsigned su = in[(size_t)node * 64 + lane];  // self-loop
    float2 acc = {bf_lo(su), bf_hi(su)};
    int b = rowptr[node], e = rowptr[node + 1];
    int j = b;
    for (; j + 7 < e; j += 8) {
        int s0 = eidx[j],     s1 = eidx[j + 1], s2 = eidx[j + 2], s3 = eidx[j + 3];
        int s4 = eidx[j + 4], s5 = eidx[j + 5], s6 = eidx[j + 6], s7 = eidx[j + 7];
        unsigned u0 = in[(size_t)s0 * 64 + lane];
        unsigned u1 = in[(size_t)s1 * 64 + lane];
        unsigned u2 = in[(size_t)s2 * 64 + lane];
        unsigned u3 = in[(size_t)s3 * 64 + lane];
        unsigned u4 = in[(size_t)s4 * 64 + lane];
        unsigned u5 = in[(size_t)s5 * 64 + lane];
        unsigned u6 = in[(size_t)s6 * 64 + lane];
        unsigned u7 = in[(size_t)s7 * 64 + lane];
        acc.x += bf_lo(u0) + bf_lo(u1) + bf_lo(u2) + bf_lo(u3)
               + bf_lo(u4) + bf_lo(u5) + bf_lo(u6) + bf_lo(u7);
        acc.y += bf_hi(u0) + bf_hi(u1) + bf_hi(u2) + bf_hi(u3)
               + bf_hi(u4) + bf_hi(u5) + bf_hi(u6) + bf_hi(u7);
    }
    for (; j + 3 < e; j += 4) {
        int s0 = eidx[j], s1 = eidx[j + 1], s2 = eidx[j + 2], s3 = eidx[j + 3];
        unsigned u0 = in[(size_t)s0 * 64 + lane];
        unsigned u1 = in[(size_t)s1 * 64 + lane];
        unsigned u2 = in[(size_t)s2 * 64 + lane];
        unsigned u3 = in[(size_t)s3 * 64 + lane];
        acc.x += bf_lo(u0) + bf_lo(u1) + bf_lo(u2) + bf_lo(u3);
        acc.y += bf_hi(u0) + bf_hi(u1) + bf_hi(u2) + bf_hi(u3);
    }
    for (; j < e; ++j) {
        unsigned u0 = in[(size_t)eidx[j] * 64 + lane];
        acc.x += bf_lo(u0);
        acc.y += bf_hi(u0);
    }
    out[(size_t)node * 64 + lane] = pack_bf16(acc.x, acc.y);
}

// ---------- GEMM1 via MFMA: h1 = hBb @ W1 + b1, fused BN sum/sumsq ----------
__global__ __launch_bounds__(256) void k_gemm1(
    const unsigned* __restrict__ hBb, const ushort* __restrict__ w1t,
    const float* __restrict__ b1, float* __restrict__ h1,
    float* __restrict__ ssum, float* __restrict__ ssq) {
    __shared__ __align__(16) ushort wT[DIM * 136];
    __shared__ float redS[4 * DIM];
    __shared__ float redQ[4 * DIM];
    int tid = threadIdx.x;
    for (int i = tid; i < DIM * 136 / 8; i += 256)
        ((uint4*)wT)[i] = ((const uint4*)w1t)[i];
    for (int i = tid; i < 4 * DIM; i += 256) { redS[i] = 0.f; redQ[i] = 0.f; }
    __syncthreads();

    int wid = tid >> 6, lane = tid & 63;
    int cl = lane & 15, kg = lane >> 4;
    int tile = blockIdx.x * 4 + wid;
    if (tile < NN / 16) {
        int rbase = tile * 16;
        const uint4* arow = (const uint4*)(hBb + (size_t)(rbase + cl) * 64);
        f32x4 acc[8];
        #pragma unroll
        for (int ct = 0; ct < 8; ++ct) acc[ct] = (f32x4){0.f, 0.f, 0.f, 0.f};
        #pragma unroll
        for (int kk = 0; kk < 4; ++kk) {
            union { uint4 u; bf16x8 f; } a;
            a.u = arow[kk * 4 + kg];
            #pragma unroll
            for (int ct = 0; ct < 8; ++ct) {
                union { uint4 u; bf16x8 f; } bb;
                bb.u = *(const uint4*)&wT[(ct * 16 + cl) * 136 + kk * 32 + kg * 8];
                acc[ct] = __builtin_amdgcn_mfma_f32_16x16x32_bf16(a.f, bb.f, acc[ct], 0, 0, 0);
            }
        }
        #pragma unroll
        for (int ct = 0; ct < 8; ++ct) {
            int col = ct * 16 + cl;
            float bias = b1[col];
            float s = 0.f, q = 0.f;
            #pragma unroll
            for (int i = 0; i < 4; ++i) {
                float v = acc[ct][i] + bias;
                h1[(size_t)(rbase + kg * 4 + i) * DIM + col] = v;
                s += v; q += v * v;
            }
            s += __shfl_xor(s, 16); s += __shfl_xor(s, 32);
            q += __shfl_xor(q, 16); q += __shfl_xor(q, 32);
            if (kg == 0) { redS[wid * DIM + col] = s; redQ[wid * DIM + col] = q; }
        }
    }
    __syncthreads();
    if (tid < DIM) {
        float S = redS[tid] + redS[DIM + tid] + redS[2 * DIM + tid] + redS[3 * DIM + tid];
        float Q = redQ[tid] + redQ[DIM + tid] + redQ[2 * DIM + tid] + redQ[3 * DIM + tid];
        atomicAdd(&ssum[tid], S);
        atomicAdd(&ssq[tid], Q);
    }
}

// ---------- GEMM2 with inline BN-stats finalize + fused BN+SELU on input ----------
__global__ __launch_bounds__(256) void k_gemm2(const float* __restrict__ h,
                                               const float* __restrict__ W2,
                                               const float* __restrict__ ssum,
                                               const float* __restrict__ ssq,
                                               const float* __restrict__ gamma,
                                               const float* __restrict__ beta,
                                               unsigned* __restrict__ tb) {
    __shared__ float w[DIM * NC];
    __shared__ float scl[DIM], shl[DIM];
    for (int i = threadIdx.x * 4; i < DIM * NC; i += 1024)
        *(float4*)&w[i] = *(const float4*)&W2[i];
    if (threadIdx.x < DIM) {
        int c = threadIdx.x;
        float mu = ssum[c] / (float)NN;
        float var = ssq[c] / (float)NN - mu * mu;
        float rs = rsqrtf(var + BN_EPS);
        float sc = rs * gamma[c];
        scl[c] = sc;
        shl[c] = beta[c] - mu * sc;
    }
    __syncthreads();

    int c0 = (threadIdx.x & 7) * 4;
    int rg = threadIdx.x >> 3;  // 0..31
    int r0 = blockIdx.x * 128 + rg * 4;
    if (r0 >= NN) return;
    const float* h0 = h + (size_t)r0 * DIM;
    float4 a0 = {0, 0, 0, 0}, a1 = {0, 0, 0, 0}, a2 = {0, 0, 0, 0}, a3 = {0, 0, 0, 0};
    #pragma unroll 4
    for (int k4 = 0; k4 < DIM / 4; ++k4) {
        float4 sc = *(const float4*)&scl[k4 * 4];
        float4 sh = *(const float4*)&shl[k4 * 4];
        float4 hv0 = *(const float4*)&h0[k4 * 4];
        float4 hv1 = *(const float4*)&h0[DIM + k4 * 4];
        float4 hv2 = *(const float4*)&h0[2 * DIM + k4 * 4];
        float4 hv3 = *(const float4*)&h0[3 * DIM + k4 * 4];
        BNSELU4(hv0, sc, sh)
        BNSELU4(hv1, sc, sh)
        BNSELU4(hv2, sc, sh)
        BNSELU4(hv3, sc, sh)
        float4 w0 = *(const float4*)&w[(k4 * 4 + 0) * NC + c0];
        float4 w1 = *(const float4*)&w[(k4 * 4 + 1) * NC + c0];
        float4 w2 = *(const float4*)&w[(k4 * 4 + 2) * NC + c0];
        float4 w3 = *(const float4*)&w[(k4 * 4 + 3) * NC + c0];
        FMA16(a0, hv0, w0, w1, w2, w3)
        FMA16(a1, hv1, w0, w1, w2, w3)
        FMA16(a2, hv2, w0, w1, w2, w3)
        FMA16(a3, hv3, w0, w1, w2, w3)
    }
    ((uint2*)tb)[((size_t)r0 * 16 + c0 / 2) / 2]       = make_uint2(pack_bf16(a0.x, a0.y), pack_bf16(a0.z, a0.w));
    ((uint2*)tb)[((size_t)(r0 + 1) * 16 + c0 / 2) / 2] = make_uint2(pack_bf16(a1.x, a1.y), pack_bf16(a1.z, a1.w));
    ((uint2*)tb)[((size_t)(r0 + 2) * 16 + c0 / 2) / 2] = make_uint2(pack_bf16(a2.x, a2.y), pack_bf16(a2.z, a2.w));
    ((uint2*)tb)[((size_t)(r0 + 3) * 16 + c0 / 2) / 2] = make_uint2(pack_bf16(a3.x, a3.y), pack_bf16(a3.z, a3.w));
}

// ---------- fused gather(bf16, 32-wide) + bias + softmax ----------
__global__ __launch_bounds__(256) void k_gsoftmax(const unsigned* __restrict__ tb,
                                                  const float* __restrict__ b2,
                                                  const int* __restrict__ rowptr,
                                                  const ushort* __restrict__ eidx,
                                                  float* __restrict__ out) {
    int node = blockIdx.x * 4 + (threadIdx.x >> 6);
    if (node >= NN) return;
    int lane = threadIdx.x & 63;
    int c2 = lane & 15;       // class pair index
    int g = lane >> 4;        // 0..3: edge-list quarter
    float2 acc = {0.f, 0.f};
    if (g == 0) {             // self-loop once
        unsigned u = tb[(size_t)node * 16 + c2];
        acc.x = bf_lo(u); acc.y = bf_hi(u);
    }
    int b = rowptr[node], e = rowptr[node + 1];
    int j = b + g;
    for (; j + 4 < e; j += 8) {
        int s0 = eidx[j];
        int s1 = eidx[j + 4];
        unsigned u0 = tb[(size_t)s0 * 16 + c2];
        unsigned u1 = tb[(size_t)s1 * 16 + c2];
        acc.x += bf_lo(u0) + bf_lo(u1);
        acc.y += bf_hi(u0) + bf_hi(u1);
    }
    if (j < e) {
        unsigned u = tb[(size_t)eidx[j] * 16 + c2];
        acc.x += bf_lo(u);
        acc.y += bf_hi(u);
    }
    acc.x += __shfl_xor(acc.x, 16); acc.x += __shfl_xor(acc.x, 32);
    acc.y += __shfl_xor(acc.y, 16); acc.y += __shfl_xor(acc.y, 32);
    acc.x += b2[2 * c2];
    acc.y += b2[2 * c2 + 1];
    float m = fmaxf(acc.x, acc.y);
    #pragma unroll
    for (int off = 8; off; off >>= 1) m = fmaxf(m, __shfl_xor(m, off, 16));
    float2 ex = {__expf(acc.x - m), __expf(acc.y - m)};
    float s = ex.x + ex.y;
    #pragma unroll
    for (int off = 8; off; off >>= 1) s += __shfl_xor(s, off, 16);
    float inv = 1.f / s;
    if (g == 0)
        *(float2*)&out[(size_t)node * NC + 2 * c2] = make_float2(ex.x * inv, ex.y * inv);
}

extern "C" void kernel_launch(void* const* d_in, const int* in_sizes, int n_in,
                              void* d_out, int out_size, void* d_ws, size_t ws_size,
                              hipStream_t stream) {
    const float* x     = (const float*)d_in[0];
    const void*  eraw  = d_in[1];
    const float* W1    = (const float*)d_in[2];
    const float* b1    = (const float*)d_in[3];
    const float* gamma = (const float*)d_in[4];
    const float* beta  = (const float*)d_in[5];
    const float* W2    = (const float*)d_in[6];
    const float* b2    = (const float*)d_in[7];
    float* out = (float*)d_out;

    // workspace layout (16B-aligned)
    float*    regA = (float*)d_ws;                    // 25.6 MB
    unsigned* xb   = (unsigned*)regA;                 // NN*64 uints (bf16 x)
    unsigned* hAb  = xb + (size_t)NN * 64;            // NN*64 uints (bf16 agg1)
    float*    h1   = regA;                            // gemm1 out, overlays xb/hAb
    float*    regB = regA + (size_t)NN * DIM;         // 25.6 MB
    unsigned* pairs= (unsigned*)regB;                 // NE uints (CSR phase only)
    unsigned* hBb  = (unsigned*)regB;                 // NN*64 uints (bf16 agg2)
    unsigned* tb   = (unsigned*)(regB + (size_t)NN * 64);  // NN*16 uints (bf16 t)
    ushort* eidx = (ushort*)(regB + (size_t)NN * DIM); // NE ushorts
    int* rowptr = (int*)(eidx + NE);                  // NN+4 (padded)
    int* cnt    = rowptr + NN + 4;                    // CB*NBLK
    int* tot    = cnt + CB * NBLK;                    // 784
    int* cbase  = tot + 784;                          // 784 (uses CB+1)
    float* ssum  = (float*)(cbase + 784);             // DIM
    float* ssq   = ssum + DIM;                        // DIM
    ushort* w1t  = (ushort*)(ssq + DIM);              // 128*136 bf16

    // merged prep (cvt + w1t + zero + bucket-histogram) — fills the machine
    k_prep<<<PREP_BLOCKS + NBLK, 256, 0, stream>>>(
        (const float4*)x, (uint2*)xb, W1, w1t, ssum, eraw, cnt);
    k_colscan<<<CB, 64, 0, stream>>>(cnt, tot);
    k_cscan<<<1, 64, 0, stream>>>(tot, cbase, rowptr);
    k_cscatter2<<<NBLK, 256, 0, stream>>>(eraw, cnt, cbase, pairs);
    k_bucket<<<CB, 256, 0, stream>>>(pairs, cbase, rowptr, eidx);

    const int gather_blocks = (NN + 3) / 4;
    // agg1: hAb = xb + gather(xb)        (bf16)
    k_gather_bf<<<gather_blocks, 256, 0, stream>>>(xb, hAb, rowptr, eidx);
    // agg2: hBb = hAb + gather(hAb)      (bf16, feeds MFMA)
    k_gather_bf<<<gather_blocks, 256, 0, stream>>>(hAb, hBb, rowptr, eidx);
    // gemm1 (MFMA) + BN stats: h1 = hBb @ W1 + b1
    k_gemm1<<<(NN / 16 + 3) / 4, 256, 0, stream>>>(hBb, w1t, b1, h1, ssum, ssq);
    // layer 2 reordered: tb = bf16(selu(bn(h1)) @ W2), out = softmax(gather(tb) + b2)
    k_gemm2<<<(NN + 127) / 128, 256, 0, stream>>>(h1, W2, ssum, ssq, gamma, beta, tb);
    k_gsoftmax<<<gather_blocks, 256, 0, stream>>>(tb, b2, rowptr, eidx, out);
}